// Round 6
// baseline (39.533 us; speedup 1.0000x reference)
//
#include <hip/hip_runtime.h>

#define NP 64          // z_vals per ray
#define M  62          // w_mid count = searched cdf prefix length
#define RPB 4          // rays per block (one wave each)

// Select component c of (a0,a1,a2) via static ternaries (no indexable
// aggregate -> no scratch; R3's lesson).
__device__ __forceinline__ float sel3(int c, float a0, float a1, float a2) {
    return (c == 0) ? a0 : ((c == 1) ? a1 : a2);
}

// Fully register/shuffle-resident: zero __shared__, zero barriers.
// All cross-lane traffic is ds_bpermute (conflict-free), all global stores
// contiguous per instruction (dwordx4 / dword).
__global__ __launch_bounds__(256) void nerf_fine_kernel(
    const float* __restrict__ rays_o,
    const float* __restrict__ rays_d,
    const float* __restrict__ weights,
    const float* __restrict__ z_vals,
    float* __restrict__ pts,        // [N,128,3]
    float* __restrict__ z_all_out,  // [N,128]
    int N)
{
    const int lane = threadIdx.x & 63;
    const int w    = threadIdx.x >> 6;
    const int ray  = blockIdx.x * RPB + w;
    if (ray >= N) return;

    // ---- loads (z/w coalesced 256B/wave; ray scalars broadcast-uniform) ----
    const float zv  = z_vals [(size_t)ray * NP + lane];
    const float wt  = weights[(size_t)ray * NP + lane];
    const float rd0 = rays_d[(size_t)ray * 3 + 0];
    const float rd1 = rays_d[(size_t)ray * 3 + 1];
    const float rd2 = rays_d[(size_t)ray * 3 + 2];
    const float ro0 = rays_o[(size_t)ray * 3 + 0];
    const float ro1 = rays_o[(size_t)ray * 3 + 1];
    const float ro2 = rays_o[(size_t)ray * 3 + 2];

    // binsv_l = z_mid[l] = 0.5*(z_l + z_{l+1}), valid l in [0,63)
    const float binsv = 0.5f * (zv + __shfl_down(zv, 1));

    // w_mid[l] = weights[l+1] + EPS_W (l < 62), wave inclusive scan (6 shuffles)
    float v = __shfl_down(wt, 1) + 1e-5f;
    v = (lane < M) ? v : 0.0f;
    #pragma unroll
    for (int off = 1; off < 64; off <<= 1) {
        float t = __shfl_up(v, off);
        if (lane >= off) v += t;
    }
    const float rtot = __builtin_amdgcn_rcpf(__shfl(v, 63)); // v_rcp_f32, 1 ulp
    const float cdfv = v * rtot;        // lane l holds cdf[l+1], l in [0,62]

    // ---- inverse-CDF: u = lane/63, searchsorted(cdf[0..61], u, 'right') ----
    const float u = (float)lane * (1.0f / 63.0f);
    int lo = 0, hi = M;
    #pragma unroll
    for (int it = 0; it < 6; ++it) {                 // ceil(log2(62)) = 6
        const int mid = (lo + hi) >> 1;
        float cv = __shfl(cdfv, mid - 1);            // junk if mid==0 (masked)
        cv = (mid == 0) ? -1.0f : cv;                // cdf[0]=0 <= u: force le
        const bool le  = (cv <= u);
        const bool act = lo < hi;
        lo = (act &&  le) ? mid + 1 : lo;
        hi = (act && !le) ? mid     : hi;
    }
    const int above = lo;                            // [1,62]
    const int below = above - 1;                     // [0,61]
    const float ca = __shfl(cdfv, above - 1);        // cdf[above]
    float cb = __shfl(cdfv, below - 1);              // cdf[below]
    cb = (below == 0) ? 0.0f : cb;
    const float bb = __shfl(binsv, below);
    const float ba = __shfl(binsv, above);
    float denom = ca - cb;
    denom = (denom < 1e-5f) ? 1.0f : denom;
    const float t  = (u - cb) * __builtin_amdgcn_rcpf(denom);
    const float zs = fmaf(t, ba - bb, bb);           // sorted across lanes

    // ---- bitonic merge of two sorted 64-seqs, all in registers ----
    float lov, hiv;
    {
        const float t0 = __shfl_xor(zs, 63);         // zs[63-lane]
        lov = fminf(zv, t0);
        hiv = fmaxf(zv, t0);
        #pragma unroll
        for (int d = 32; d >= 1; d >>= 1) {
            const float pl = __shfl_xor(lov, d);
            const float ph = __shfl_xor(hiv, d);
            const bool up  = (lane & d) != 0;
            lov = up ? fmaxf(lov, pl) : fminf(lov, pl);
            hiv = up ? fmaxf(hiv, ph) : fminf(hiv, ph);
        }
    }
    // lov = z_all[lane], hiv = z_all[64+lane]

    // ---- z_all: straight from registers, 2 x 256B contiguous ----
    float* zo = z_all_out + (size_t)ray * 128;
    zo[lane]      = lov;
    zo[64 + lane] = hiv;

    // ---- pts: contiguous dwordx4 stores ----
    // float4 #j covers ids 4j..4j+3; k = id/3 takes only {t, t+1} with
    // t = (4j)/3; component c_i = (r+i) mod 3 with r = j mod 3.
    float4* p4 = (float4*)(pts + (size_t)ray * 384);  // 96 float4/ray

    // ALL shuffles full-wave (outside divergence) so bpermute never pulls
    // from exec-masked lanes.
    #define PTS4(J, Q, BOTHSRC)                                              \
    {                                                                        \
        const int j_  = (J);                                                 \
        const int t_  = (4 * j_) / 3;                                        \
        const int r_  = 4 * j_ - 3 * t_;          /* = j_ mod 3 */           \
        const int i0_ = t_ & 63, i1_ = (t_ + 1) & 63;                        \
        float za_, zb_;                                                      \
        if (BOTHSRC) {                                                       \
            const float gla_ = __shfl(lov, i0_), gha_ = __shfl(hiv, i0_);    \
            const float glb_ = __shfl(lov, i1_), ghb_ = __shfl(hiv, i1_);    \
            za_ = (t_     < 64) ? gla_ : gha_;                               \
            zb_ = (t_ + 1 < 64) ? glb_ : ghb_;                               \
        } else {                                  /* t_ >= 64 always */      \
            za_ = __shfl(hiv, i0_);                                          \
            zb_ = __shfl(hiv, i1_);                                          \
        }                                                                    \
        const int r1_ = (r_ == 2) ? 0 : r_ + 1;                              \
        const int r2_ = (r_ == 0) ? 2 : r_ - 1;                              \
        const float rdA_ = sel3(r_,  rd0, rd1, rd2);                         \
        const float roA_ = sel3(r_,  ro0, ro1, ro2);                         \
        const float rdB_ = sel3(r1_, rd0, rd1, rd2);                         \
        const float roB_ = sel3(r1_, ro0, ro1, ro2);                         \
        const float rdC_ = sel3(r2_, rd0, rd1, rd2);                         \
        const float roC_ = sel3(r2_, ro0, ro1, ro2);                         \
        const float z1_ = (r_ == 2) ? zb_ : za_;                             \
        const float z2_ = (r_ == 0) ? za_ : zb_;                             \
        Q.x = fmaf(za_, rdA_, roA_);                                         \
        Q.y = fmaf(z1_, rdB_, roB_);                                         \
        Q.z = fmaf(z2_, rdC_, roC_);                                         \
        Q.w = fmaf(zb_, rdA_, roA_);                                         \
    }

    float4 q0;                     // j = lane: t in [0,84] -> needs both srcs
    PTS4(lane, q0, true);
    float4 q1;                     // j = 64+lane (valid lanes<32): t>=85 -> hiv
    PTS4(64 + lane, q1, false);

    p4[lane] = q0;                               // 1 KB contiguous
    if (lane < 32) p4[64 + lane] = q1;           // 512 B contiguous
    #undef PTS4
}

extern "C" void kernel_launch(void* const* d_in, const int* in_sizes, int n_in,
                              void* d_out, int out_size, void* d_ws, size_t ws_size,
                              hipStream_t stream) {
    const float* rays_o  = (const float*)d_in[0];
    const float* rays_d  = (const float*)d_in[1];
    const float* weights = (const float*)d_in[2];
    const float* z_vals  = (const float*)d_in[3];

    const int N = in_sizes[2] / NP;                      // weights is [N, 64]
    float* pts   = (float*)d_out;                        // [N,128,3]
    float* z_all = (float*)d_out + (size_t)N * 128 * 3;  // [N,128]

    const int blocks = (N + RPB - 1) / RPB;
    nerf_fine_kernel<<<blocks, 256, 0, stream>>>(rays_o, rays_d, weights, z_vals,
                                                 pts, z_all, N);
}

// Round 7
// 32.039 us; speedup vs baseline: 1.2339x; 1.2339x over previous
//
#include <hip/hip_runtime.h>

#define NP 64          // z_vals per ray
#define M  62          // w_mid count = searched cdf prefix length
#define RPB 4          // rays per block (one wave each)

// One DPP-scan step: x += dpp_shift(x). OOB/masked lanes contribute 0
// (old=0 + bound_ctrl). Compile-time ctrl/row_mask per gfx9 wave64 rules.
template<int CTRL, int RM>
__device__ __forceinline__ float dpp_add(float x) {
    const int y = __builtin_amdgcn_update_dpp(0, __float_as_int(x), CTRL, RM, 0xF, true);
    return x + __int_as_float(y);
}

// Fully register-resident: zero __shared__, zero barriers. Scan is pure-VALU
// DPP (LLVM buildScan sequence); only the binary search + bitonic merge use
// the LDS pipe (bpermute/swizzle), unavoidable variable-index cross-lane.
__global__ __launch_bounds__(256) void nerf_fine_kernel(
    const float* __restrict__ rays_o,
    const float* __restrict__ rays_d,
    const float* __restrict__ weights,
    const float* __restrict__ z_vals,
    float* __restrict__ pts,        // [N,128,3]
    float* __restrict__ z_all_out,  // [N,128]
    int N)
{
    const int lane = threadIdx.x & 63;
    const int w    = threadIdx.x >> 6;
    const int ray  = blockIdx.x * RPB + w;
    if (ray >= N) return;

    // ---- loads: z[l], z[l+1], w[l+1] as three coalesced streams (the
    // shifted loads hit the same cache lines: 0 extra HBM, kills 2 bpermutes)
    const int lp1 = (lane < 63) ? (lane + 1) : 63;     // clamp: no OOB on last ray
    const float zv  = z_vals [(size_t)ray * NP + lane];
    const float zsh = z_vals [(size_t)ray * NP + lp1];
    const float wsh = weights[(size_t)ray * NP + lp1];

    const float rd0 = rays_d[(size_t)ray * 3 + 0];
    const float rd1 = rays_d[(size_t)ray * 3 + 1];
    const float rd2 = rays_d[(size_t)ray * 3 + 2];
    const float ro0 = rays_o[(size_t)ray * 3 + 0];
    const float ro1 = rays_o[(size_t)ray * 3 + 1];
    const float ro2 = rays_o[(size_t)ray * 3 + 2];

    // binsv_l = z_mid[l] = 0.5*(z_l + z_{l+1}), valid l in [0,63)
    const float binsv = 0.5f * (zv + zsh);

    // w_mid[l] = weights[l+1] + EPS_W (l < 62), zeros above
    float v = (lane < M) ? (wsh + 1e-5f) : 0.0f;

    // ---- wave64 inclusive scan, pure DPP (no LDS pipe) ----
    v = dpp_add<0x111, 0xF>(v);   // row_shr:1
    v = dpp_add<0x112, 0xF>(v);   // row_shr:2
    v = dpp_add<0x114, 0xF>(v);   // row_shr:4
    v = dpp_add<0x118, 0xF>(v);   // row_shr:8
    v = dpp_add<0x142, 0xA>(v);   // row_bcast:15 -> rows 1,3
    v = dpp_add<0x143, 0xC>(v);   // row_bcast:31 -> rows 2,3

    const float total = __int_as_float(__builtin_amdgcn_readlane(__float_as_int(v), 63));
    const float rtot  = __builtin_amdgcn_rcpf(total);        // v_rcp_f32, 1 ulp
    const float cdfv  = v * rtot;       // lane l holds cdf[l+1], l in [0,62]

    // ---- inverse-CDF: u = lane/63, searchsorted(cdf[0..61], u, 'right') ----
    const float u = (float)lane * (1.0f / 63.0f);
    int lo = 0, hi = M;
    #pragma unroll
    for (int it = 0; it < 6; ++it) {                 // ceil(log2(62)) = 6
        const int mid = (lo + hi) >> 1;
        float cv = __shfl(cdfv, mid - 1);            // junk if mid==0 (masked)
        cv = (mid == 0) ? -1.0f : cv;                // cdf[0]=0 <= u: force le
        const bool le  = (cv <= u);
        const bool act = lo < hi;
        lo = (act &&  le) ? mid + 1 : lo;
        hi = (act && !le) ? mid     : hi;
    }
    const int above = lo;                            // [1,62]
    const int below = above - 1;                     // [0,61]
    const float ca = __shfl(cdfv, above - 1);        // cdf[above]
    float cb = __shfl(cdfv, below - 1);              // cdf[below]
    cb = (below == 0) ? 0.0f : cb;
    const float bb = __shfl(binsv, below);
    const float ba = __shfl(binsv, above);
    float denom = ca - cb;
    denom = (denom < 1e-5f) ? 1.0f : denom;
    const float t  = (u - cb) * __builtin_amdgcn_rcpf(denom);
    const float zs = fmaf(t, ba - bb, bb);           // sorted across lanes

    // ---- bitonic merge of two sorted 64-seqs, all in registers ----
    float lov, hiv;
    {
        const float t0 = __shfl_xor(zs, 63);         // zs[63-lane]
        lov = fminf(zv, t0);
        hiv = fmaxf(zv, t0);
        #pragma unroll
        for (int d = 32; d >= 1; d >>= 1) {
            const float pl = __shfl_xor(lov, d);
            const float ph = __shfl_xor(hiv, d);
            const bool up  = (lane & d) != 0;
            lov = up ? fmaxf(lov, pl) : fminf(lov, pl);
            hiv = up ? fmaxf(hiv, ph) : fminf(hiv, ph);
        }
    }
    // lov = z_all[lane], hiv = z_all[64+lane]

    // ---- z_all: straight from registers, coalesced ----
    float* zo = z_all_out + (size_t)ray * 128;
    zo[lane]      = lov;
    zo[64 + lane] = hiv;

    // ---- pts: zero-shuffle epilogue; lane l owns rows l and 64+l ----
    // (stride-12 dword stores; the wave fully covers a contiguous span, L2
    //  assembles full lines — proven non-limiting by the R6 A/B)
    float* pp = pts + (size_t)ray * 384 + 3 * lane;
    pp[0]   = fmaf(lov, rd0, ro0);
    pp[1]   = fmaf(lov, rd1, ro1);
    pp[2]   = fmaf(lov, rd2, ro2);
    pp[192] = fmaf(hiv, rd0, ro0);   // row 64+l = +192 floats
    pp[193] = fmaf(hiv, rd1, ro1);
    pp[194] = fmaf(hiv, rd2, ro2);
}

extern "C" void kernel_launch(void* const* d_in, const int* in_sizes, int n_in,
                              void* d_out, int out_size, void* d_ws, size_t ws_size,
                              hipStream_t stream) {
    const float* rays_o  = (const float*)d_in[0];
    const float* rays_d  = (const float*)d_in[1];
    const float* weights = (const float*)d_in[2];
    const float* z_vals  = (const float*)d_in[3];

    const int N = in_sizes[2] / NP;                      // weights is [N, 64]
    float* pts   = (float*)d_out;                        // [N,128,3]
    float* z_all = (float*)d_out + (size_t)N * 128 * 3;  // [N,128]

    const int blocks = (N + RPB - 1) / RPB;
    nerf_fine_kernel<<<blocks, 256, 0, stream>>>(rays_o, rays_d, weights, z_vals,
                                                 pts, z_all, N);
}